// Round 9
// baseline (79.837 us; speedup 1.0000x reference)
//
#include <hip/hip_runtime.h>

#define BB 32
#define SS 22
#define NN 2048
#define HH 8
#define DKK 8
#define PP 6

__global__ __attribute__((amdgpu_flat_work_group_size(256, 256),
                          amdgpu_waves_per_eu(4, 4)))
// waves_per_eu(4,4): sets the register allocator's occupancy TARGET to 4 waves/EU
// (128-VGPR budget). R8 showed __launch_bounds__(256,4) only sets the floor: the
// allocator still targeted 8 waves (VGPR pegged at exactly 64 = 512/8, spilled).
// Combined with the asm pins below (which outlaw remat-by-reload), the only legal
// allocation is true residency of K/V state in ~95-110 VGPRs.
void mha_kernel(
    const float* __restrict__ q, const float* __restrict__ k, const float* __restrict__ v,
    const int* __restrict__ mask,
    const float* __restrict__ Wq, const float* __restrict__ bq,
    const float* __restrict__ Wk, const float* __restrict__ bk,
    const float* __restrict__ Wv, const float* __restrict__ bv,
    const float* __restrict__ Wc, const float* __restrict__ bc,
    const float* __restrict__ Wf, const float* __restrict__ bf,
    float* __restrict__ out)
{
    __shared__ float Ms[HH][9];
    __shared__ float Us[HH][3];
    __shared__ unsigned mb[SS];
    __shared__ float wflL[HH][SS];   // Wf rows; rows 6,7 zero
    __shared__ float offL[HH];       // bf[p] + bc0*sum_s Wf[p,s]; rows 6,7 zero

    const int tid = threadIdx.x;
    // --- per-block precompute of the collapsed weight forms ---
    if (tid < 72) {
        int hh = tid / 9, ij = tid - hh * 9, i = ij / 3, j = ij - i * 3;
        float acc = 0.f;
        for (int d = 0; d < DKK; ++d) {
            int c = hh * DKK + d;
            float a  = (i == 0) ? Wq[2 * c] : (i == 1) ? Wq[2 * c + 1] : bq[c];
            float bb = (j == 0) ? Wk[2 * c] : (j == 1) ? Wk[2 * c + 1] : bk[c];
            acc = fmaf(a, bb, acc);
        }
        Ms[hh][ij] = acc * (1.4426950408889634f / 64.f);  // fold 1/DK^2 and log2(e)
    } else if (tid < 96) {
        int r = tid - 72, hh = r / 3, j = r - hh * 3;
        float acc = 0.f;
        for (int d = 0; d < DKK; ++d) {
            int c = hh * DKK + d;
            float a = (j == 0) ? Wv[2 * c] : (j == 1) ? Wv[2 * c + 1] : bv[c];
            acc = fmaf(a, Wc[c], acc);
        }
        Us[hh][j] = acc;
    } else if (tid < 96 + SS) {
        int s = tid - 96;
        unsigned bitsv = 0;
        for (int t = 0; t < SS; ++t)
            if (mask[s * SS + t] != 0) bitsv |= (1u << t);
        mb[s] = bitsv;
    } else if (tid < 96 + SS + HH) {
        int p = tid - (96 + SS);
        float acc = 0.f;
        if (p < PP) {
            float ssum = 0.f;
            for (int t = 0; t < SS; ++t) ssum += Wf[p * SS + t];
            acc = fmaf(bc[0], ssum, bf[p]);
        }
        offL[p] = acc;
    }
    for (int idx = tid; idx < HH * SS; idx += 256) {
        int hh = idx / SS, t = idx - hh * SS;
        wflL[hh][t] = (hh < PP) ? Wf[hh * SS + t] : 0.f;
    }
    __syncthreads();

    // Lane layout: g = lane&7 -> 8 consecutive (b,n) pairs (one 64B line per load
    // instr; head-groups duplicate addresses -> broadcast). h = (lane>>3)&7 -> head.
    const int g    = tid & 7;
    const int h    = (tid >> 3) & 7;
    const int wid  = tid >> 6;                        // wave within block (0..3)
    const int pair = blockIdx.x * 32 + wid * 8 + g;   // 32 pairs per block
    const int b    = pair >> 11;                      // NN = 2048
    const int n    = pair & (NN - 1);

    const float2* qp = (const float2*)q;
    const float2* kp = (const float2*)k;
    const float2* vp = (const float2*)v;
    const int base = (b * SS) * NN + n;   // + s*NN per row

    const float m00 = Ms[h][0], m01 = Ms[h][1], m02 = Ms[h][2];
    const float m10 = Ms[h][3], m11 = Ms[h][4], m12 = Ms[h][5];
    const float m20 = Ms[h][6], m21 = Ms[h][7], m22 = Ms[h][8];
    const float u0 = Us[h][0], u1 = Us[h][1], u2 = Us[h][2];

    // K rows and w MUST stay register-resident. Each empty asm makes the value an
    // opaque VGPR def: the allocator can neither rematerialize it by re-issuing
    // the global load (R2/R4/R6 plateau) nor fold it away.
    float2 kx[SS];
    float  w[SS];
    float wsA = 0.f, wsB = 0.f;
#pragma unroll
    for (int t = 0; t < SS; ++t) {
        kx[t] = kp[base + t * NN];
        float2 vv = vp[base + t * NN];
        w[t] = fmaf(vv.x, u0, fmaf(vv.y, u1, u2));
        asm volatile("" : "+v"(kx[t].x), "+v"(kx[t].y), "+v"(w[t]));
        if (t & 1) wsB += w[t]; else wsA += w[t];
    }
    const float wsum = wsA + wsB;

    float o = offL[h];
#pragma unroll
    for (int s = 0; s < SS; ++s) {
        const unsigned bits = (unsigned)__builtin_amdgcn_readfirstlane((int)mb[s]);
        const float2 qq = qp[base + s * NN];   // streamed; prefetched by the unroll
        float cs;
        if (bits == 0) {
            // fully-masked row: reference softmax degenerates to uniform 1/S
            cs = wsum * (1.f / (float)SS);
        } else {
            const float g0 = fmaf(qq.x, m00, fmaf(qq.y, m10, m20));
            const float g1 = fmaf(qq.x, m01, fmaf(qq.y, m11, m21));
            const float g2 = fmaf(qq.x, m02, fmaf(qq.y, m12, m22));
            float sA = 0.f, sB = 0.f, dA = 0.f, dB = 0.f;
#pragma unroll
            for (int t = 0; t < SS; ++t) {
                if (bits & (1u << t)) {   // wave-uniform branch; skips ~half the exps
                    float att = fmaf(g0, kx[t].x, fmaf(g1, kx[t].y, g2));
                    float e = __builtin_amdgcn_exp2f(att);
                    if (t & 1) { sB += e; dB = fmaf(e, w[t], dB); }
                    else       { sA += e; dA = fmaf(e, w[t], dA); }
                }
                // masked entries: exp(-2^15 - m) == 0.0f exactly in the reference
            }
            cs = (dA + dB) * __builtin_amdgcn_rcpf(sA + sB);
        }
        // merge heads: butterfly across the 8 h-lanes (masks 8,16,32);
        // independent across s -> overlaps with next s's compute
        cs += __shfl_xor(cs, 8);
        cs += __shfl_xor(cs, 16);
        cs += __shfl_xor(cs, 32);
        o = fmaf(cs, wflL[h][s], o);   // epilogue folded in (rows 6,7 zero)
    }

    if (h < PP)
        out[(b * PP + h) * NN + n] = o;
}

extern "C" void kernel_launch(void* const* d_in, const int* in_sizes, int n_in,
                              void* d_out, int out_size, void* d_ws, size_t ws_size,
                              hipStream_t stream) {
    const float* q  = (const float*)d_in[0];
    const float* k  = (const float*)d_in[1];
    const float* v  = (const float*)d_in[2];
    const int* mask = (const int*)d_in[3];
    const float* Wq = (const float*)d_in[4];
    const float* bq = (const float*)d_in[5];
    const float* Wk = (const float*)d_in[6];
    const float* bk = (const float*)d_in[7];
    const float* Wv = (const float*)d_in[8];
    const float* bv = (const float*)d_in[9];
    const float* Wc = (const float*)d_in[10];
    const float* bc = (const float*)d_in[11];
    const float* Wf = (const float*)d_in[12];
    const float* bf = (const float*)d_in[13];
    float* out = (float*)d_out;

    dim3 grid(BB * NN * HH / 256), block(256);
    hipLaunchKernelGGL(mha_kernel, grid, block, 0, stream,
                       q, k, v, mask, Wq, bq, Wk, bk, Wv, bv, Wc, bc, Wf, bf, out);
}

// Round 10
// 52.279 us; speedup vs baseline: 1.5271x; 1.5271x over previous
//
#include <hip/hip_runtime.h>

#define BB 32
#define SS 22
#define NN 2048
#define HH 8
#define DKK 8
#define PP 6

__global__ __launch_bounds__(256, 8) void mha_kernel(
    const float* __restrict__ q, const float* __restrict__ k, const float* __restrict__ v,
    const int* __restrict__ mask,
    const float* __restrict__ Wq, const float* __restrict__ bq,
    const float* __restrict__ Wk, const float* __restrict__ bk,
    const float* __restrict__ Wv, const float* __restrict__ bv,
    const float* __restrict__ Wc, const float* __restrict__ bc,
    const float* __restrict__ Wf, const float* __restrict__ bf,
    float* __restrict__ out)
{
    __shared__ float Ms[HH][9];
    __shared__ float Us[HH][3];
    __shared__ unsigned mb[SS];
    __shared__ float wflL[HH][SS];                 // Wf rows; rows 6,7 zero
    __shared__ float offL[HH];                     // bf[p] + bc0*sum_s Wf[p,s]; rows 6,7 zero
    __shared__ __align__(16) float4 kvL[SS][32];   // {kx,ky,vx,vy} per (t, pair-in-block)

    const int tid = threadIdx.x;
    const float2* qp = (const float2*)q;
    const float2* kp = (const float2*)k;
    const float2* vp = (const float2*)v;

    // --- per-block precompute of the collapsed weight forms ---
    if (tid < 72) {
        int hh = tid / 9, ij = tid - hh * 9, i = ij / 3, j = ij - i * 3;
        float acc = 0.f;
        for (int d = 0; d < DKK; ++d) {
            int c = hh * DKK + d;
            float a  = (i == 0) ? Wq[2 * c] : (i == 1) ? Wq[2 * c + 1] : bq[c];
            float bb = (j == 0) ? Wk[2 * c] : (j == 1) ? Wk[2 * c + 1] : bk[c];
            acc = fmaf(a, bb, acc);
        }
        Ms[hh][ij] = acc * (1.4426950408889634f / 64.f);  // fold 1/DK^2 and log2(e)
    } else if (tid < 96) {
        int r = tid - 72, hh = r / 3, j = r - hh * 3;
        float acc = 0.f;
        for (int d = 0; d < DKK; ++d) {
            int c = hh * DKK + d;
            float a = (j == 0) ? Wv[2 * c] : (j == 1) ? Wv[2 * c + 1] : bv[c];
            acc = fmaf(a, Wc[c], acc);
        }
        Us[hh][j] = acc;
    } else if (tid < 96 + SS) {
        int s = tid - 96;
        unsigned bitsv = 0;
        for (int t = 0; t < SS; ++t)
            if (mask[s * SS + t] != 0) bitsv |= (1u << t);
        mb[s] = bitsv;
    } else if (tid < 96 + SS + HH) {
        int p = tid - (96 + SS);
        float acc = 0.f;
        if (p < PP) {
            float ssum = 0.f;
            for (int t = 0; t < SS; ++t) ssum += Wf[p * SS + t];
            acc = fmaf(bc[0], ssum, bf[p]);
        }
        offL[p] = acc;
    }
    for (int idx = tid; idx < HH * SS; idx += 256) {
        int hh = idx / SS, t = idx - hh * SS;
        wflL[hh][t] = (hh < PP) ? Wf[hh * SS + t] : 0.f;
    }
    // stage K/V for this block's 32 pairs into LDS (coalesced 8B/lane loads)
    for (int idx = tid; idx < SS * 32; idx += 256) {
        int t = idx >> 5, p = idx & 31;
        int pr = blockIdx.x * 32 + p;
        int bb_ = pr >> 11, nn_ = pr & (NN - 1);
        int gix = (bb_ * SS + t) * NN + nn_;
        float2 kk = kp[gix], vv = vp[gix];
        kvL[t][p] = make_float4(kk.x, kk.y, vv.x, vv.y);
    }
    __syncthreads();

    // Lane layout: g = lane&7 -> 8 consecutive (b,n) pairs; h = (lane>>3)&7 -> head.
    // kvL[t][pin] per wave: 8 distinct float4 x 8-way broadcast -> conflict-free.
    const int g    = tid & 7;
    const int h    = (tid >> 3) & 7;
    const int wid  = tid >> 6;                        // wave within block (0..3)
    const int pin  = wid * 8 + g;                     // pair-in-block (0..31)
    const int pair = blockIdx.x * 32 + pin;
    const int b    = pair >> 11;                      // NN = 2048
    const int n    = pair & (NN - 1);
    const int base = (b * SS) * NN + n;               // + s*NN per q row

    const float m00 = Ms[h][0], m01 = Ms[h][1], m02 = Ms[h][2];
    const float m10 = Ms[h][3], m11 = Ms[h][4], m12 = Ms[h][5];
    const float m20 = Ms[h][6], m21 = Ms[h][7], m22 = Ms[h][8];
    const float u0 = Us[h][0], u1 = Us[h][1], u2 = Us[h][2];

    float o = offL[h];
#pragma unroll
    for (int s = 0; s < SS; ++s) {
        const unsigned bits = (unsigned)__builtin_amdgcn_readfirstlane((int)mb[s]);
        const float2 qq = qp[base + s * NN];          // streamed via L1 (8-lane broadcast)
        float cs;
        if (bits == 0) {
            // fully-masked row: softmax degenerates to uniform 1/S (correctness only)
            float SVx = 0.f, SVy = 0.f;
#pragma unroll
            for (int t = 0; t < SS; ++t) { float4 kv = kvL[t][pin]; SVx += kv.z; SVy += kv.w; }
            cs = fmaf(u0, SVx, fmaf(u1, SVy, (float)SS * u2)) * (1.f / (float)SS);
        } else {
            const float g0 = fmaf(qq.x, m00, fmaf(qq.y, m10, m20));
            const float g1 = fmaf(qq.x, m01, fmaf(qq.y, m11, m21));
            const float g2 = fmaf(qq.x, m02, fmaf(qq.y, m12, m22));
            float S = 0.f, Dx = 0.f, Dy = 0.f;
            // STATIC unrolled walk: all active t's ds_reads issue back-to-back (ILP),
            // wave-uniform skip branches drop ~half the exps. No register home needed
            // for K/V (LDS is the home) -> no remat, no spill, ~50 VGPRs.
#pragma unroll
            for (int t = 0; t < SS; ++t) {
                if (bits & (1u << t)) {
                    float4 kv = kvL[t][pin];          // broadcast ds_read_b128
                    float e = __builtin_amdgcn_exp2f(fmaf(g0, kv.x, fmaf(g1, kv.y, g2)));
                    S += e;
                    Dx = fmaf(e, kv.z, Dx);
                    Dy = fmaf(e, kv.w, Dy);
                }
                // masked entries: exp(-2^15 - m) == 0.0f exactly in the reference
            }
            // dot = sum_t e*(u0*vx+u1*vy+u2) = u0*Dx + u1*Dy + u2*S
            cs = fmaf(u0, Dx, fmaf(u1, Dy, u2 * S)) * __builtin_amdgcn_rcpf(S);
        }
        // merge heads: butterfly across the 8 h-lanes (masks 8,16,32)
        cs += __shfl_xor(cs, 8);
        cs += __shfl_xor(cs, 16);
        cs += __shfl_xor(cs, 32);
        o = fmaf(cs, wflL[h][s], o);   // epilogue folded in (rows 6,7 zero)
    }

    if (h < PP)
        out[(b * PP + h) * NN + n] = o;
}

extern "C" void kernel_launch(void* const* d_in, const int* in_sizes, int n_in,
                              void* d_out, int out_size, void* d_ws, size_t ws_size,
                              hipStream_t stream) {
    const float* q  = (const float*)d_in[0];
    const float* k  = (const float*)d_in[1];
    const float* v  = (const float*)d_in[2];
    const int* mask = (const int*)d_in[3];
    const float* Wq = (const float*)d_in[4];
    const float* bq = (const float*)d_in[5];
    const float* Wk = (const float*)d_in[6];
    const float* bk = (const float*)d_in[7];
    const float* Wv = (const float*)d_in[8];
    const float* bv = (const float*)d_in[9];
    const float* Wc = (const float*)d_in[10];
    const float* bc = (const float*)d_in[11];
    const float* Wf = (const float*)d_in[12];
    const float* bf = (const float*)d_in[13];
    float* out = (float*)d_out;

    dim3 grid(BB * NN / 32), block(256);
    hipLaunchKernelGGL(mha_kernel, grid, block, 0, stream,
                       q, k, v, mask, Wq, bq, Wk, bk, Wv, bv, Wc, bc, Wf, bf, out);
}